// Round 14
// baseline (268.119 us; speedup 1.0000x reference)
//
#include <hip/hip_runtime.h>
#include <cstdint>
#include <cstddef>

#define B_   2
#define S_   21760
#define M_   (B_ * S_)     // 43520
#define D_   256
#define DFF_ 1024
#define EPS_ 1e-5f

typedef __attribute__((ext_vector_type(8))) short short8;
typedef __attribute__((ext_vector_type(4))) float f32x4;
typedef __attribute__((ext_vector_type(2))) float f32x2;

__device__ __forceinline__ ushort f2bf(float f) {
    uint x = __float_as_uint(f);
    return (ushort)((x + 0x7fffu + ((x >> 16) & 1u)) >> 16);
}
__device__ __forceinline__ float bf2f(ushort u) {
    return __uint_as_float(((uint)u) << 16);
}
__device__ __forceinline__ uint8_t f2f8(float v) {
    return (uint8_t)(__builtin_amdgcn_cvt_pk_fp8_f32(v, v, 0, false) & 0xff);
}
// fp8 GEMM operand k-slot swizzle: 16B slots XORed by (row&3) within 64B groups
__device__ __forceinline__ int kswz(int c, int row) {
    return (c & ~63) | ((((c >> 4) & 3) ^ (row & 3)) << 4) | (c & 15);
}

// ---------------------------------------------------------------------------
// Merged prep: blocks [0,10880) do src/q bf16 converts; rest do weight
// converts (bf16 transposed for val/oa/ff1; fp8 swizzled for out/ff2) + bias.
// ---------------------------------------------------------------------------
#define CVT_BLOCKS 10880
__global__ __launch_bounds__(256) void prep_all(
    const float* __restrict__ src, const float* __restrict__ pos,
    ushort* __restrict__ sb, ushort* __restrict__ qb,
    const float* __restrict__ Wval, const float* __restrict__ Woff,
    const float* __restrict__ Wattn, const float* __restrict__ Wout,
    const float* __restrict__ Wff1, const float* __restrict__ Wff2,
    const float* __restrict__ boff, const float* __restrict__ battn,
    ushort* __restrict__ WT, uint8_t* __restrict__ WT8,
    float* __restrict__ bias_oa)
{
    if (blockIdx.x < CVT_BLOCKS) {
        const size_t i = ((size_t)blockIdx.x * 256 + threadIdx.x) * 4;
        const float4 s = *(const float4*)(src + i);
        const float4 p = *(const float4*)(pos + i);
        ushort4 so, qo;
        so.x = f2bf(s.x); so.y = f2bf(s.y); so.z = f2bf(s.z); so.w = f2bf(s.w);
        qo.x = f2bf(s.x + p.x); qo.y = f2bf(s.y + p.y);
        qo.z = f2bf(s.z + p.z); qo.w = f2bf(s.w + p.w);
        *(ushort4*)(sb + i) = so;
        *(ushort4*)(qb + i) = qo;
        return;
    }
    const int i = (blockIdx.x - CVT_BLOCKS) * 256 + threadIdx.x;
    if (i < 65536) {                        // W_val -> bf16 [n][k]
        const int n = i >> 8, k = i & 255;
        WT[i] = f2bf(Wval[(size_t)k * 256 + n]);
    } else if (i < 163840) {                // off|attn -> bf16 [384][256]
        const int j = i - 65536;
        const int n = j >> 8, k = j & 255;
        WT[i] = (n < 256) ? f2bf(Woff[(size_t)k * 256 + n])
                          : f2bf(Wattn[(size_t)k * 128 + (n - 256)]);
    } else if (i < 425984) {                // W_ff1 -> bf16 [1024][256]
        const int j = i - 163840;
        const int n = j >> 8, k = j & 255;
        WT[i] = f2bf(Wff1[(size_t)k * 1024 + n]);
    } else if (i < 491520) {                // W_out -> fp8 [256][256] swizzled
        const int j = i - 425984;
        const int n = j >> 8, k = j & 255;
        WT8[(size_t)n * 256 + kswz(k, n)] = f2f8(Wout[(size_t)k * 256 + n]);
    } else if (i < 753664) {                // W_ff2 -> fp8 [256][1024] swizzled
        const int j = i - 491520;
        const int n = j >> 10, k = j & 1023;
        WT8[65536 + (size_t)n * 1024 + kswz(k, n)] = f2f8(Wff2[(size_t)k * 256 + n]);
    } else if (i < 753664 + 384) {
        const int j = i - 753664;
        bias_oa[j] = (j < 256) ? boff[j] : battn[j - 256];
    }
}

// ---------------------------------------------------------------------------
// bf16 MFMA GEMM: 128x128 tile, BK=64, XOR-swizzled LDS (both sides).
// mode 0: bf16 row-major C. mode 2: fp8 head-major value layout.
// mode 3: fp8 row-major with k-slot swizzle (feeds mgemm8's A).
// ---------------------------------------------------------------------------
__global__ __launch_bounds__(256) void mgemm(
    const ushort* __restrict__ A, const ushort* __restrict__ WT,
    const float* __restrict__ bias, ushort* __restrict__ C,
    int M, int N, int K, int relu, int mode)
{
    __shared__ __align__(16) ushort Als[128 * 64];
    __shared__ __align__(16) ushort Bls[128 * 64];

    const int nwg = gridDim.x;
    const int bid = blockIdx.x;
    const int q8 = nwg >> 3, r8 = nwg & 7;
    const int xcd = bid & 7, blk = bid >> 3;
    const int wg = (xcd < r8 ? xcd * (q8 + 1) : r8 * (q8 + 1) + (xcd - r8) * q8) + blk;
    const int gx = N >> 7;
    const int n0 = (wg % gx) << 7;
    const int m0 = (wg / gx) << 7;

    const int tid = threadIdx.x;
    const int wv = tid >> 6, ln = tid & 63;
    const int wm = wv >> 1, wn = wv & 1;

    const int srow = ln >> 3;
    const int scol = ((ln & 7) ^ srow) * 8;

    f32x4 acc[4][4];
    const f32x4 zz = {0.f, 0.f, 0.f, 0.f};
    #pragma unroll
    for (int i = 0; i < 4; i++)
        #pragma unroll
        for (int j = 0; j < 4; j++) acc[i][j] = zz;

    const int fr = ln & 15, qq = ln >> 4;

    for (int k0 = 0; k0 < K; k0 += 64) {
        __syncthreads();
        #pragma unroll
        for (int r = 0; r < 4; ++r) {
            const int c = r * 4 + wv;
            const ushort* ga = A + (size_t)(m0 + c * 8 + srow) * K + k0 + scol;
            __builtin_amdgcn_global_load_lds(
                (const __attribute__((address_space(1))) uint*)ga,
                (__attribute__((address_space(3))) uint*)(Als + c * 512), 16, 0, 0);
            const ushort* gb = WT + (size_t)(n0 + c * 8 + srow) * K + k0 + scol;
            __builtin_amdgcn_global_load_lds(
                (const __attribute__((address_space(1))) uint*)gb,
                (__attribute__((address_space(3))) uint*)(Bls + c * 512), 16, 0, 0);
        }
        __syncthreads();

        #pragma unroll
        for (int kk = 0; kk < 2; kk++) {
            short8 af[4], bfr[4];
            #pragma unroll
            for (int i = 0; i < 4; i++) {
                const int row = wm * 64 + i * 16 + fr;
                af[i] = *(const short8*)&Als[row * 64 + (((kk * 4 + qq) ^ (row & 7)) * 8)];
            }
            #pragma unroll
            for (int j = 0; j < 4; j++) {
                const int row = wn * 64 + j * 16 + fr;
                bfr[j] = *(const short8*)&Bls[row * 64 + (((kk * 4 + qq) ^ (row & 7)) * 8)];
            }
            #pragma unroll
            for (int i = 0; i < 4; i++)
                #pragma unroll
                for (int j = 0; j < 4; j++)
                    acc[i][j] = __builtin_amdgcn_mfma_f32_16x16x32_bf16(
                        af[i], bfr[j], acc[i][j], 0, 0, 0);
        }
    }

    uint8_t* C8 = (uint8_t*)C;
    const int rq = (ln >> 4) * 4;
    #pragma unroll
    for (int j = 0; j < 4; j++) {
        const int col = n0 + wn * 64 + j * 16 + fr;
        const float bv = bias[col];
        #pragma unroll
        for (int i = 0; i < 4; i++) {
            #pragma unroll
            for (int r = 0; r < 4; r++) {
                const int row = m0 + wm * 64 + i * 16 + rq + r;
                float v = acc[i][j][r] + bv;
                if (relu) v = fmaxf(v, 0.f);
                if (mode == 0) {
                    C[(size_t)row * N + col] = f2bf(v);
                } else if (mode == 2) {
                    const int bb = (row >= S_) ? 1 : 0;
                    const int loc = row - bb * S_;
                    const int hh = col >> 5, ch = col & 31;
                    C8[((size_t)(bb * 8 + hh) * S_ + loc) * 32 + ch] = f2f8(v);
                } else {  // mode 3: fp8 row-major, k-slot swizzled for mgemm8
                    C8[(size_t)row * N + kswz(col, row)] = f2f8(v);
                }
            }
        }
    }
}

// ---------------------------------------------------------------------------
// fp8 MFMA GEMM: C[M,N] bf16 = A8[M,K](fp8, k-slot swizzled) @ W8[N,K]^T + b.
// 128x128 tile, 64-byte K-stage (2 x 16x16x32 fp8 MFMA), 16 KB LDS.
// Linear LDS dest (gload 16B/lane); read-side XOR matches producer swizzle.
// ---------------------------------------------------------------------------
__global__ __launch_bounds__(256) void mgemm8(
    const uint8_t* __restrict__ A, const uint8_t* __restrict__ W8,
    const float* __restrict__ bias, ushort* __restrict__ C,
    int M, int N, int K)
{
    __shared__ __align__(16) uint8_t Als[128 * 64];
    __shared__ __align__(16) uint8_t Bls[128 * 64];

    const int nwg = gridDim.x;
    const int bid = blockIdx.x;
    const int q8 = nwg >> 3, r8 = nwg & 7;
    const int xcd = bid & 7, blk = bid >> 3;
    const int wg = (xcd < r8 ? xcd * (q8 + 1) : r8 * (q8 + 1) + (xcd - r8) * q8) + blk;
    const int gx = N >> 7;
    const int n0 = (wg % gx) << 7;
    const int m0 = (wg / gx) << 7;

    const int tid = threadIdx.x;
    const int wv = tid >> 6, ln = tid & 63;
    const int wm = wv >> 1, wn = wv & 1;
    const int fr = ln & 15, qq = ln >> 4;

    f32x4 acc[4][4];
    const f32x4 zz = {0.f, 0.f, 0.f, 0.f};
    #pragma unroll
    for (int i = 0; i < 4; i++)
        #pragma unroll
        for (int j = 0; j < 4; j++) acc[i][j] = zz;

    for (int k0 = 0; k0 < K; k0 += 64) {
        __syncthreads();
        #pragma unroll
        for (int r = 0; r < 2; ++r) {
            const int row = r * 64 + (tid >> 2);
            const int sl = (tid & 3) * 16;
            const uint8_t* ga = A + (size_t)(m0 + row) * K + k0 + sl;
            __builtin_amdgcn_global_load_lds(
                (const __attribute__((address_space(1))) uint*)ga,
                (__attribute__((address_space(3))) uint*)(Als + row * 64 + sl), 16, 0, 0);
            const uint8_t* gb = W8 + (size_t)(n0 + row) * K + k0 + sl;
            __builtin_amdgcn_global_load_lds(
                (const __attribute__((address_space(1))) uint*)gb,
                (__attribute__((address_space(3))) uint*)(Bls + row * 64 + sl), 16, 0, 0);
        }
        __syncthreads();

        #pragma unroll
        for (int kk = 0; kk < 2; kk++) {
            long af[4], bfr[4];
            #pragma unroll
            for (int i = 0; i < 4; i++) {
                const int row = wm * 64 + i * 16 + fr;
                af[i] = *(const long*)&Als[row * 64 +
                        ((((kk * 2 + (qq >> 1)) ^ (row & 3)) << 4) | ((qq & 1) * 8))];
            }
            #pragma unroll
            for (int j = 0; j < 4; j++) {
                const int row = wn * 64 + j * 16 + fr;
                bfr[j] = *(const long*)&Bls[row * 64 +
                        ((((kk * 2 + (qq >> 1)) ^ (row & 3)) << 4) | ((qq & 1) * 8))];
            }
            #pragma unroll
            for (int i = 0; i < 4; i++)
                #pragma unroll
                for (int j = 0; j < 4; j++)
                    acc[i][j] = __builtin_amdgcn_mfma_f32_16x16x32_fp8_fp8(
                        af[i], bfr[j], acc[i][j], 0, 0, 0);
        }
    }

    const int rq = (ln >> 4) * 4;
    #pragma unroll
    for (int j = 0; j < 4; j++) {
        const int col = n0 + wn * 64 + j * 16 + fr;
        const float bv = bias[col];
        #pragma unroll
        for (int i = 0; i < 4; i++) {
            #pragma unroll
            for (int r = 0; r < 4; r++) {
                const int row = m0 + wm * 64 + i * 16 + rq + r;
                C[(size_t)row * N + col] = f2bf(acc[i][j][r] + bv);
            }
        }
    }
}

// ---------------------------------------------------------------------------
// Residual + LayerNorm, wave-per-row, vectorized, no LDS/barriers.
// ---------------------------------------------------------------------------
__global__ __launch_bounds__(256) void ln_row(
    const ushort* __restrict__ a16, const ushort* __restrict__ r16,
    const float* __restrict__ g, const float* __restrict__ be,
    float* __restrict__ o32, ushort* __restrict__ o16)
{
    const int wv = threadIdx.x >> 6, ln = threadIdx.x & 63;
    const int row = blockIdx.x * 4 + wv;
    const int col = ln * 4;
    const size_t base = (size_t)row * 256 + col;

    const ushort4 av = *(const ushort4*)(a16 + base);
    const ushort4 rv = *(const ushort4*)(r16 + base);
    float v0 = bf2f(av.x) + bf2f(rv.x);
    float v1 = bf2f(av.y) + bf2f(rv.y);
    float v2 = bf2f(av.z) + bf2f(rv.z);
    float v3 = bf2f(av.w) + bf2f(rv.w);

    float s = v0 + v1 + v2 + v3;
    float s2 = v0 * v0 + v1 * v1 + v2 * v2 + v3 * v3;
    #pragma unroll
    for (int o = 32; o > 0; o >>= 1) {
        s  += __shfl_down(s, o);
        s2 += __shfl_down(s2, o);
    }
    s = __shfl(s, 0);
    s2 = __shfl(s2, 0);
    const float mean = s * (1.f / 256.f);
    const float var = s2 * (1.f / 256.f) - mean * mean;
    const float rstd = rsqrtf(var + EPS_);

    const float4 gv = *(const float4*)(g + col);
    const float4 bv = *(const float4*)(be + col);
    const float o0 = (v0 - mean) * rstd * gv.x + bv.x;
    const float o1 = (v1 - mean) * rstd * gv.y + bv.y;
    const float o2 = (v2 - mean) * rstd * gv.z + bv.z;
    const float o3 = (v3 - mean) * rstd * gv.w + bv.w;

    if (o32) {
        float4 o; o.x = o0; o.y = o1; o.z = o2; o.w = o3;
        *(float4*)(o32 + base) = o;
    } else {
        ushort4 o; o.x = f2bf(o0); o.y = f2bf(o1); o.z = f2bf(o2); o.w = f2bf(o3);
        *(ushort4*)(o16 + base) = o;
    }
}

// ---------------------------------------------------------------------------
// Deformable sampling v8b: (b,h)-partitioned, L2-resident; fp8 OUTPUT in
// mgemm8's k-slot-swizzled layout.
// ---------------------------------------------------------------------------
__global__ __launch_bounds__(256) void sample8(
    const uint8_t* __restrict__ value, const ushort* __restrict__ offaw,
    const float* __restrict__ refp, uint8_t* __restrict__ samp8)
{
    const int bid = blockIdx.x;
    const int wg = (bid & 7) * 680 + (bid >> 3);
    const int bh = wg / 340;
    const int qc = wg - bh * 340;
    const int b = bh >> 3, h = bh & 7;

    const int tid = threadIdx.x;
    const int g = tid >> 2, cg = tid & 3;
    const int q = b * S_ + qc * 64 + g;
    const int half = cg >> 1;
    const int gbase = (tid & 63) & ~3;

    const int Wl = 128 >> cg;
    const float fW = (float)Wl;
    const int st = (cg == 0) ? 0 : (cg == 1) ? 16384 : (cg == 2) ? 20480 : 21504;

    const ushort* awq = offaw + (size_t)q * 384 + 256 + h * 16 + cg * 4;
    const uint2 lg = *(const uint2*)awq;
    const float l0 = bf2f((ushort)(lg.x & 0xffff)), l1 = bf2f((ushort)(lg.x >> 16));
    const float l2 = bf2f((ushort)(lg.y & 0xffff)), l3 = bf2f((ushort)(lg.y >> 16));
    float mx = fmaxf(fmaxf(l0, l1), fmaxf(l2, l3));
    mx = fmaxf(mx, __shfl_xor(mx, 1));
    mx = fmaxf(mx, __shfl_xor(mx, 2));
    const float e0 = __expf(l0 - mx), e1 = __expf(l1 - mx);
    const float e2 = __expf(l2 - mx), e3 = __expf(l3 - mx);
    float sm = e0 + e1 + e2 + e3;
    sm += __shfl_xor(sm, 1);
    sm += __shfl_xor(sm, 2);
    const float inv = 1.f / sm;
    const float aj[4] = {e0 * inv, e1 * inv, e2 * inv, e3 * inv};

    const ushort* ofq = offaw + (size_t)q * 384 + h * 32 + cg * 8;
    const uint4 of = *(const uint4*)ofq;
    const uint ou[4] = {of.x, of.y, of.z, of.w};
    const float rx = refp[(size_t)q * 8 + cg * 2];
    const float ry = refp[(size_t)q * 8 + cg * 2 + 1];

    int  rxo[8];
    uint wpk[8];
    #pragma unroll
    for (int j = 0; j < 4; j++) {
        const float ox = bf2f((ushort)(ou[j] & 0xffff));
        const float oy = bf2f((ushort)(ou[j] >> 16));
        const float x = fmaf(rx, fW, ox) - 0.5f;
        const float y = fmaf(ry, fW, oy) - 0.5f;
        const float fx0 = floorf(x), fy0 = floorf(y);
        const float dx = x - fx0, dy = y - fy0;
        const int x0 = (int)fx0, y0 = (int)fy0;

        const int bx = min(max(x0, 0), Wl - 2);
        const float mwx0 = ((x0 >= 0) & (x0 < Wl)) ? (1.f - dx) : 0.f;
        const float mwx1 = ((x0 + 1 >= 0) & (x0 + 1 < Wl)) ? dx : 0.f;
        const int xc0 = min(max(x0, 0), Wl - 1);
        const int xc1 = min(max(x0 + 1, 0), Wl - 1);
        const float wAx = (xc0 == bx ? mwx0 : 0.f) + (xc1 == bx ? mwx1 : 0.f);
        const float wBx = (xc0 == bx + 1 ? mwx0 : 0.f) + (xc1 == bx + 1 ? mwx1 : 0.f);

        const int yc0 = min(max(y0, 0), Wl - 1);
        const int yc1 = min(max(y0 + 1, 0), Wl - 1);
        const float mwy0 = ((y0 >= 0) & (y0 < Wl)) ? (1.f - dy) : 0.f;
        const float mwy1 = ((y0 + 1 >= 0) & (y0 + 1 < Wl)) ? dy : 0.f;

        const float a = aj[j];
        rxo[2 * j]     = (st + yc0 * Wl + bx) * 32;
        rxo[2 * j + 1] = (st + yc1 * Wl + bx) * 32;
        wpk[2 * j]     = (uint)f2bf(a * wAx * mwy0) | ((uint)f2bf(a * wBx * mwy0) << 16);
        wpk[2 * j + 1] = (uint)f2bf(a * wAx * mwy1) | ((uint)f2bf(a * wBx * mwy1) << 16);
    }

    const uint8_t* vb = value + (size_t)(b * 8 + h) * S_ * 32 + cg * 16;
    f32x2 acc[8];
    #pragma unroll
    for (int k = 0; k < 8; k++) acc[k] = (f32x2){0.f, 0.f};

    #pragma unroll
    for (int ol = 0; ol < 4; ol++) {
        const int srcl = gbase + ol;
        #pragma unroll
        for (int r = 0; r < 8; r++) {
            const int  rix = __shfl(rxo[r], srcl, 64);
            const uint wp  = (uint)__shfl((int)wpk[r], srcl, 64);
            const float wv = bf2f((ushort)(half ? (wp >> 16) : (wp & 0xffffu)));
            const uint4 u = *(const uint4*)(vb + rix);
            const f32x2 w2 = {wv, wv};
            acc[0] += w2 * __builtin_amdgcn_cvt_pk_f32_fp8((int)u.x, false);
            acc[1] += w2 * __builtin_amdgcn_cvt_pk_f32_fp8((int)u.x, true);
            acc[2] += w2 * __builtin_amdgcn_cvt_pk_f32_fp8((int)u.y, false);
            acc[3] += w2 * __builtin_amdgcn_cvt_pk_f32_fp8((int)u.y, true);
            acc[4] += w2 * __builtin_amdgcn_cvt_pk_f32_fp8((int)u.z, false);
            acc[5] += w2 * __builtin_amdgcn_cvt_pk_f32_fp8((int)u.z, true);
            acc[6] += w2 * __builtin_amdgcn_cvt_pk_f32_fp8((int)u.w, false);
            acc[7] += w2 * __builtin_amdgcn_cvt_pk_f32_fp8((int)u.w, true);
        }
    }

    #pragma unroll
    for (int k = 0; k < 8; k++) {
        acc[k].x += __shfl_xor(acc[k].x, 2);
        acc[k].y += __shfl_xor(acc[k].y, 2);
    }

    f32x2 r0, r1, r2, r3;
    if (half == 0) { r0 = acc[0]; r1 = acc[1]; r2 = acc[2]; r3 = acc[3]; }
    else           { r0 = acc[4]; r1 = acc[5]; r2 = acc[6]; r3 = acc[7]; }

    // fp8 pack + k-slot swizzled store (8 channels = 8 bytes)
    const uint p0 = (uint)__builtin_amdgcn_cvt_pk_fp8_f32(r0.x, r0.y, 0, false);
    const uint p1 = (uint)__builtin_amdgcn_cvt_pk_fp8_f32(r1.x, r1.y, 0, false);
    const uint p2 = (uint)__builtin_amdgcn_cvt_pk_fp8_f32(r2.x, r2.y, 0, false);
    const uint p3 = (uint)__builtin_amdgcn_cvt_pk_fp8_f32(r3.x, r3.y, 0, false);
    uint2 o8;
    o8.x = (p0 & 0xffffu) | (p1 << 16);
    o8.y = (p2 & 0xffffu) | (p3 << 16);
    const int c = h * 32 + (cg & 1) * 16 + half * 8;
    *(uint2*)(samp8 + (size_t)q * 256 + kswz(c, q)) = o8;
}

// ---------------------------------------------------------------------------
extern "C" void kernel_launch(void* const* d_in, const int* in_sizes, int n_in,
                              void* d_out, int out_size, void* d_ws, size_t ws_size,
                              hipStream_t stream)
{
    const float* src    = (const float*)d_in[0];
    const float* pos    = (const float*)d_in[1];
    const float* refp   = (const float*)d_in[2];
    const float* W_off  = (const float*)d_in[5];
    const float* b_off  = (const float*)d_in[6];
    const float* W_attn = (const float*)d_in[7];
    const float* b_attn = (const float*)d_in[8];
    const float* W_val  = (const float*)d_in[9];
    const float* b_val  = (const float*)d_in[10];
    const float* W_out  = (const float*)d_in[11];
    const float* b_out  = (const float*)d_in[12];
    const float* g1     = (const float*)d_in[13];
    const float* be1    = (const float*)d_in[14];
    const float* W_ff1  = (const float*)d_in[15];
    const float* b_ff1  = (const float*)d_in[16];
    const float* W_ff2  = (const float*)d_in[17];
    const float* b_ff2  = (const float*)d_in[18];
    const float* g2     = (const float*)d_in[19];
    const float* be2    = (const float*)d_in[20];
    float* out = (float*)d_out;

    const size_t szMDh = (size_t)M_ * 256 * 2;      // 22,282,240 B
    const size_t szOAh = (size_t)M_ * 384 * 2;      // 33,423,360 B

    char* ws = (char*)d_ws;
    ushort*  WT      = (ushort*)ws;                 // val@0, oa@65536, ff1@163840
    ushort*  WT_val  = WT;
    ushort*  WT_oa   = WT + 65536;
    ushort*  WT_ff1  = WT + 163840;
    uint8_t* WT8     = (uint8_t*)(ws + 851968);     // out8@0, ff28@65536
    uint8_t* WT8_out = WT8;
    uint8_t* WT8_ff2 = WT8 + 65536;
    float*   bias_oa = (float*)(ws + 1507328);

    const size_t o_src  = 2097152;
    const size_t o_q    = o_src + szMDh;
    const size_t o_val  = o_q   + szMDh;
    const size_t o_oa   = o_val + szMDh;
    const size_t o_x    = o_oa  + szOAh;
    const size_t o_ffn  = o_x   + szMDh;            // total 146.9 MB (proven fit)

    ushort*  src_bf = (ushort*)(ws + o_src);
    ushort*  q_bf   = (ushort*)(ws + o_q);
    ushort*  val_f8 = (ushort*)(ws + o_val);
    ushort*  offaw  = (ushort*)(ws + o_oa);
    ushort*  x_bf   = (ushort*)(ws + o_x);
    ushort*  ffn_bf = (ushort*)(ws + o_ffn);
    uint8_t* samp8  = (uint8_t*)q_bf;    // q_bf dead after offaw GEMM (11.1 MB)
    ushort*  attn_bf = val_f8;           // val dead after sampling
    uint8_t* h8     = (uint8_t*)src_bf;  // M*1024 B = 44.56 MB = src+q regions,
                                         // free after ln1 (samp8 dead post-attn)

    // 0) converts (src/q) + all weight converts, one dispatch
    prep_all<<<CVT_BLOCKS + 2947, 256, 0, stream>>>(
        src, pos, src_bf, q_bf,
        W_val, W_off, W_attn, W_out, W_ff1, W_ff2, b_off, b_attn,
        WT, WT8, bias_oa);
    // 1) value = src @ W_val + b_val  (fp8 head-major)
    mgemm<<<2 * (M_ / 128), 256, 0, stream>>>(src_bf, WT_val, b_val, val_f8, M_, 256, 256, 0, 2);
    // 2) offaw = (src+pos) @ [W_off|W_attn] + bias
    mgemm<<<3 * (M_ / 128), 256, 0, stream>>>(q_bf, WT_oa, bias_oa, offaw, M_, 384, 256, 0, 0);
    // 3) sampling -> fp8 swizzled samp
    sample8<<<16 * 340, 256, 0, stream>>>((const uint8_t*)val_f8, offaw, refp, samp8);
    // 4) attn_out = samp8 @ W_out + b_out  (fp8 GEMM)
    mgemm8<<<2 * (M_ / 128), 256, 0, stream>>>(samp8, WT8_out, b_out, attn_bf, M_, 256, 256);
    // 5) x = LN(src_bf + attn)
    ln_row<<<M_ / 4, 256, 0, stream>>>(attn_bf, src_bf, g1, be1, nullptr, x_bf);
    // 6) FFN1: h8 = fp8(relu(x @ W_ff1 + b_ff1)), k-slot swizzled
    mgemm<<<8 * (M_ / 128), 256, 0, stream>>>(x_bf, WT_ff1, b_ff1, (ushort*)h8, M_, DFF_, 256, 1, 3);
    // 7) FFN2: ffn = h8 @ W_ff2 + b_ff2  (fp8 GEMM, K=1024)
    mgemm8<<<2 * (M_ / 128), 256, 0, stream>>>(h8, WT8_ff2, b_ff2, ffn_bf, M_, 256, DFF_);
    // 8) out = LN(x + ffn)
    ln_row<<<M_ / 4, 256, 0, stream>>>(ffn_bf, x_bf, g2, be2, out, nullptr);
}

// Round 15
// 245.396 us; speedup vs baseline: 1.0926x; 1.0926x over previous
//
#include <hip/hip_runtime.h>
#include <cstdint>
#include <cstddef>

#define B_   2
#define S_   21760
#define M_   (B_ * S_)     // 43520
#define D_   256
#define DFF_ 1024
#define EPS_ 1e-5f

typedef __attribute__((ext_vector_type(8))) short short8;
typedef __attribute__((ext_vector_type(4))) float f32x4;
typedef __attribute__((ext_vector_type(2))) float f32x2;

__device__ __forceinline__ ushort f2bf(float f) {
    uint x = __float_as_uint(f);
    return (ushort)((x + 0x7fffu + ((x >> 16) & 1u)) >> 16);
}
__device__ __forceinline__ float bf2f(ushort u) {
    return __uint_as_float(((uint)u) << 16);
}
__device__ __forceinline__ uint8_t f2f8(float v) {
    return (uint8_t)(__builtin_amdgcn_cvt_pk_fp8_f32(v, v, 0, false) & 0xff);
}
// bijective XCD-chunked swizzle (m204)
__device__ __forceinline__ int xcd_swz(int bid, int nwg) {
    const int q8 = nwg >> 3, r8 = nwg & 7;
    const int xcd = bid & 7, blk = bid >> 3;
    return (xcd < r8 ? xcd * (q8 + 1) : r8 * (q8 + 1) + (xcd - r8) * q8) + blk;
}

// ---------------------------------------------------------------------------
// Merged prep: blocks [0,10880) do src/q bf16 converts; rest do weight
// transpose+convert + bias concat (one dispatch total).
// ---------------------------------------------------------------------------
#define CVT_BLOCKS 10880
__global__ __launch_bounds__(256) void prep_all(
    const float* __restrict__ src, const float* __restrict__ pos,
    ushort* __restrict__ sb, ushort* __restrict__ qb,
    const float* __restrict__ Wval, const float* __restrict__ Woff,
    const float* __restrict__ Wattn, const float* __restrict__ Wout,
    const float* __restrict__ Wff1, const float* __restrict__ Wff2,
    const float* __restrict__ boff, const float* __restrict__ battn,
    ushort* __restrict__ WT, float* __restrict__ bias_oa)
{
    if (blockIdx.x < CVT_BLOCKS) {
        const size_t i = ((size_t)blockIdx.x * 256 + threadIdx.x) * 4;
        const float4 s = *(const float4*)(src + i);
        const float4 p = *(const float4*)(pos + i);
        ushort4 so, qo;
        so.x = f2bf(s.x); so.y = f2bf(s.y); so.z = f2bf(s.z); so.w = f2bf(s.w);
        qo.x = f2bf(s.x + p.x); qo.y = f2bf(s.y + p.y);
        qo.z = f2bf(s.z + p.z); qo.w = f2bf(s.w + p.w);
        *(ushort4*)(sb + i) = so;
        *(ushort4*)(qb + i) = qo;
        return;
    }
    const int i = (blockIdx.x - CVT_BLOCKS) * 256 + threadIdx.x;
    if (i < 65536) {
        const int n = i >> 8, k = i & 255;
        WT[i] = f2bf(Wval[(size_t)k * 256 + n]);
    } else if (i < 163840) {
        const int j = i - 65536;
        const int n = j >> 8, k = j & 255;
        WT[i] = (n < 256) ? f2bf(Woff[(size_t)k * 256 + n])
                          : f2bf(Wattn[(size_t)k * 128 + (n - 256)]);
    } else if (i < 229376) {
        const int j = i - 163840;
        const int n = j >> 8, k = j & 255;
        WT[i] = f2bf(Wout[(size_t)k * 256 + n]);
    } else if (i < 491520) {
        const int j = i - 229376;
        const int n = j >> 8, k = j & 255;
        WT[i] = f2bf(Wff1[(size_t)k * 1024 + n]);
    } else if (i < 753664) {
        const int j = i - 491520;
        const int n = j >> 10, k = j & 1023;
        WT[i] = f2bf(Wff2[(size_t)k * 256 + n]);
    } else if (i < 753664 + 384) {
        const int j = i - 753664;
        bias_oa[j] = (j < 256) ? boff[j] : battn[j - 256];
    }
}

// ---------------------------------------------------------------------------
// Shared bf16 MFMA GEMM body: 128x128 tile, BK=64, XOR-swizzled LDS
// (linear LDS dest + pre-swizzled global source col + matching read XOR).
// mode 0: bf16 row-major C. mode 2: fp8 e4m3 head-major value layout.
// Single call site per kernel -> one 32 KB LDS allocation.
// ---------------------------------------------------------------------------
__device__ __forceinline__ void gemm_body(
    const ushort* __restrict__ A, const ushort* __restrict__ WT,
    const float* __restrict__ bias, ushort* __restrict__ C,
    int N, int K, int relu, int mode, int wg)
{
    __shared__ __align__(16) ushort Als[128 * 64];
    __shared__ __align__(16) ushort Bls[128 * 64];

    const int gx = N >> 7;
    const int n0 = (wg % gx) << 7;
    const int m0 = (wg / gx) << 7;

    const int tid = threadIdx.x;
    const int wv = tid >> 6, ln = tid & 63;
    const int wm = wv >> 1, wn = wv & 1;

    const int srow = ln >> 3;
    const int scol = ((ln & 7) ^ srow) * 8;

    f32x4 acc[4][4];
    const f32x4 zz = {0.f, 0.f, 0.f, 0.f};
    #pragma unroll
    for (int i = 0; i < 4; i++)
        #pragma unroll
        for (int j = 0; j < 4; j++) acc[i][j] = zz;

    const int fr = ln & 15, qq = ln >> 4;

    for (int k0 = 0; k0 < K; k0 += 64) {
        __syncthreads();
        #pragma unroll
        for (int r = 0; r < 4; ++r) {
            const int c = r * 4 + wv;
            const ushort* ga = A + (size_t)(m0 + c * 8 + srow) * K + k0 + scol;
            __builtin_amdgcn_global_load_lds(
                (const __attribute__((address_space(1))) uint*)ga,
                (__attribute__((address_space(3))) uint*)(Als + c * 512), 16, 0, 0);
            const ushort* gb = WT + (size_t)(n0 + c * 8 + srow) * K + k0 + scol;
            __builtin_amdgcn_global_load_lds(
                (const __attribute__((address_space(1))) uint*)gb,
                (__attribute__((address_space(3))) uint*)(Bls + c * 512), 16, 0, 0);
        }
        __syncthreads();

        #pragma unroll
        for (int kk = 0; kk < 2; kk++) {
            short8 af[4], bfr[4];
            #pragma unroll
            for (int i = 0; i < 4; i++) {
                const int row = wm * 64 + i * 16 + fr;
                af[i] = *(const short8*)&Als[row * 64 + (((kk * 4 + qq) ^ (row & 7)) * 8)];
            }
            #pragma unroll
            for (int j = 0; j < 4; j++) {
                const int row = wn * 64 + j * 16 + fr;
                bfr[j] = *(const short8*)&Bls[row * 64 + (((kk * 4 + qq) ^ (row & 7)) * 8)];
            }
            #pragma unroll
            for (int i = 0; i < 4; i++)
                #pragma unroll
                for (int j = 0; j < 4; j++)
                    acc[i][j] = __builtin_amdgcn_mfma_f32_16x16x32_bf16(
                        af[i], bfr[j], acc[i][j], 0, 0, 0);
        }
    }

    uint8_t* C8 = (uint8_t*)C;
    const int rq = (ln >> 4) * 4;
    #pragma unroll
    for (int j = 0; j < 4; j++) {
        const int col = n0 + wn * 64 + j * 16 + fr;
        const float bv = bias[col];
        #pragma unroll
        for (int i = 0; i < 4; i++) {
            #pragma unroll
            for (int r = 0; r < 4; r++) {
                const int row = m0 + wm * 64 + i * 16 + rq + r;
                float v = acc[i][j][r] + bv;
                if (relu) v = fmaxf(v, 0.f);
                if (mode == 0) {
                    C[(size_t)row * N + col] = f2bf(v);
                } else {
                    const int bb = (row >= S_) ? 1 : 0;
                    const int loc = row - bb * S_;
                    const int hh = col >> 5, ch = col & 31;
                    C8[((size_t)(bb * 8 + hh) * S_ + loc) * 32 + ch] = f2f8(v);
                }
            }
        }
    }
}

// Single-job GEMM kernel
__global__ __launch_bounds__(256) void mgemm(
    const ushort* __restrict__ A, const ushort* __restrict__ WT,
    const float* __restrict__ bias, ushort* __restrict__ C,
    int M, int N, int K, int relu, int mode)
{
    const int wg = xcd_swz(blockIdx.x, gridDim.x);
    gemm_body(A, WT, bias, C, N, K, relu, mode, wg);
}

// Dual-job kernel: blocks [0,680) = value GEMM (mode 2), [680,1700) = offaw.
// Both independent (only depend on prep_all); merging overlaps their
// latency-limited tails and saves a dispatch gap.
__global__ __launch_bounds__(256) void mgemm_vo(
    const ushort* __restrict__ src_bf, const ushort* __restrict__ WT_val,
    const float* __restrict__ b_val, ushort* __restrict__ val_f8,
    const ushort* __restrict__ q_bf, const ushort* __restrict__ WT_oa,
    const float* __restrict__ bias_oa, ushort* __restrict__ offaw)
{
    const ushort *A, *WT;
    const float* bias;
    ushort* C;
    int N, mode, wg;
    if (blockIdx.x < 680) {
        A = src_bf; WT = WT_val; bias = b_val; C = val_f8;
        N = 256; mode = 2; wg = xcd_swz(blockIdx.x, 680);
    } else {
        A = q_bf; WT = WT_oa; bias = bias_oa; C = offaw;
        N = 384; mode = 0; wg = xcd_swz(blockIdx.x - 680, 1020);
    }
    gemm_body(A, WT, bias, C, N, 256, 0, mode, wg);
}

// ---------------------------------------------------------------------------
// Residual + LayerNorm, wave-per-row, vectorized, no LDS/barriers.
// ---------------------------------------------------------------------------
__global__ __launch_bounds__(256) void ln_row(
    const ushort* __restrict__ a16, const ushort* __restrict__ r16,
    const float* __restrict__ g, const float* __restrict__ be,
    float* __restrict__ o32, ushort* __restrict__ o16)
{
    const int wv = threadIdx.x >> 6, ln = threadIdx.x & 63;
    const int row = blockIdx.x * 4 + wv;
    const int col = ln * 4;
    const size_t base = (size_t)row * 256 + col;

    const ushort4 av = *(const ushort4*)(a16 + base);
    const ushort4 rv = *(const ushort4*)(r16 + base);
    float v0 = bf2f(av.x) + bf2f(rv.x);
    float v1 = bf2f(av.y) + bf2f(rv.y);
    float v2 = bf2f(av.z) + bf2f(rv.z);
    float v3 = bf2f(av.w) + bf2f(rv.w);

    float s = v0 + v1 + v2 + v3;
    float s2 = v0 * v0 + v1 * v1 + v2 * v2 + v3 * v3;
    #pragma unroll
    for (int o = 32; o > 0; o >>= 1) {
        s  += __shfl_down(s, o);
        s2 += __shfl_down(s2, o);
    }
    s = __shfl(s, 0);
    s2 = __shfl(s2, 0);
    const float mean = s * (1.f / 256.f);
    const float var = s2 * (1.f / 256.f) - mean * mean;
    const float rstd = rsqrtf(var + EPS_);

    const float4 gv = *(const float4*)(g + col);
    const float4 bv = *(const float4*)(be + col);
    const float o0 = (v0 - mean) * rstd * gv.x + bv.x;
    const float o1 = (v1 - mean) * rstd * gv.y + bv.y;
    const float o2 = (v2 - mean) * rstd * gv.z + bv.z;
    const float o3 = (v3 - mean) * rstd * gv.w + bv.w;

    if (o32) {
        float4 o; o.x = o0; o.y = o1; o.z = o2; o.w = o3;
        *(float4*)(o32 + base) = o;
    } else {
        ushort4 o; o.x = f2bf(o0); o.y = f2bf(o1); o.z = f2bf(o2); o.w = f2bf(o3);
        *(ushort4*)(o16 + base) = o;
    }
}

// ---------------------------------------------------------------------------
// Deformable sampling v8: (b,h)-partitioned blocks for L2-resident gathers.
// ---------------------------------------------------------------------------
__global__ __launch_bounds__(256) void sample8(
    const uint8_t* __restrict__ value, const ushort* __restrict__ offaw,
    const float* __restrict__ refp, ushort* __restrict__ samp)
{
    const int bid = blockIdx.x;
    const int wg = (bid & 7) * 680 + (bid >> 3);
    const int bh = wg / 340;                      // 0..15
    const int qc = wg - bh * 340;                 // q-chunk
    const int b = bh >> 3, h = bh & 7;

    const int tid = threadIdx.x;
    const int g = tid >> 2, cg = tid & 3;
    const int q = b * S_ + qc * 64 + g;           // global row in [0,M)
    const int half = cg >> 1;
    const int gbase = (tid & 63) & ~3;

    const int Wl = 128 >> cg;
    const float fW = (float)Wl;
    const int st = (cg == 0) ? 0 : (cg == 1) ? 16384 : (cg == 2) ? 20480 : 21504;

    const ushort* awq = offaw + (size_t)q * 384 + 256 + h * 16 + cg * 4;
    const uint2 lg = *(const uint2*)awq;
    const float l0 = bf2f((ushort)(lg.x & 0xffff)), l1 = bf2f((ushort)(lg.x >> 16));
    const float l2 = bf2f((ushort)(lg.y & 0xffff)), l3 = bf2f((ushort)(lg.y >> 16));
    float mx = fmaxf(fmaxf(l0, l1), fmaxf(l2, l3));
    mx = fmaxf(mx, __shfl_xor(mx, 1));
    mx = fmaxf(mx, __shfl_xor(mx, 2));
    const float e0 = __expf(l0 - mx), e1 = __expf(l1 - mx);
    const float e2 = __expf(l2 - mx), e3 = __expf(l3 - mx);
    float sm = e0 + e1 + e2 + e3;
    sm += __shfl_xor(sm, 1);
    sm += __shfl_xor(sm, 2);
    const float inv = 1.f / sm;
    const float aj[4] = {e0 * inv, e1 * inv, e2 * inv, e3 * inv};

    const ushort* ofq = offaw + (size_t)q * 384 + h * 32 + cg * 8;
    const uint4 of = *(const uint4*)ofq;
    const uint ou[4] = {of.x, of.y, of.z, of.w};
    const float rx = refp[(size_t)q * 8 + cg * 2];
    const float ry = refp[(size_t)q * 8 + cg * 2 + 1];

    int  rxo[8];
    uint wpk[8];                                  // bf16(wA) | bf16(wB)<<16
    #pragma unroll
    for (int j = 0; j < 4; j++) {
        const float ox = bf2f((ushort)(ou[j] & 0xffff));
        const float oy = bf2f((ushort)(ou[j] >> 16));
        const float x = fmaf(rx, fW, ox) - 0.5f;
        const float y = fmaf(ry, fW, oy) - 0.5f;
        const float fx0 = floorf(x), fy0 = floorf(y);
        const float dx = x - fx0, dy = y - fy0;
        const int x0 = (int)fx0, y0 = (int)fy0;

        const int bx = min(max(x0, 0), Wl - 2);
        const float mwx0 = ((x0 >= 0) & (x0 < Wl)) ? (1.f - dx) : 0.f;
        const float mwx1 = ((x0 + 1 >= 0) & (x0 + 1 < Wl)) ? dx : 0.f;
        const int xc0 = min(max(x0, 0), Wl - 1);
        const int xc1 = min(max(x0 + 1, 0), Wl - 1);
        const float wAx = (xc0 == bx ? mwx0 : 0.f) + (xc1 == bx ? mwx1 : 0.f);
        const float wBx = (xc0 == bx + 1 ? mwx0 : 0.f) + (xc1 == bx + 1 ? mwx1 : 0.f);

        const int yc0 = min(max(y0, 0), Wl - 1);
        const int yc1 = min(max(y0 + 1, 0), Wl - 1);
        const float mwy0 = ((y0 >= 0) & (y0 < Wl)) ? (1.f - dy) : 0.f;
        const float mwy1 = ((y0 + 1 >= 0) & (y0 + 1 < Wl)) ? dy : 0.f;

        const float a = aj[j];
        rxo[2 * j]     = (st + yc0 * Wl + bx) * 32;
        rxo[2 * j + 1] = (st + yc1 * Wl + bx) * 32;
        wpk[2 * j]     = (uint)f2bf(a * wAx * mwy0) | ((uint)f2bf(a * wBx * mwy0) << 16);
        wpk[2 * j + 1] = (uint)f2bf(a * wAx * mwy1) | ((uint)f2bf(a * wBx * mwy1) << 16);
    }

    const uint8_t* vb = value + (size_t)(b * 8 + h) * S_ * 32 + cg * 16;
    f32x2 acc[8];
    #pragma unroll
    for (int k = 0; k < 8; k++) acc[k] = (f32x2){0.f, 0.f};

    #pragma unroll
    for (int ol = 0; ol < 4; ol++) {
        const int srcl = gbase + ol;
        #pragma unroll
        for (int r = 0; r < 8; r++) {
            const int  rix = __shfl(rxo[r], srcl, 64);
            const uint wp  = (uint)__shfl((int)wpk[r], srcl, 64);
            const float wv = bf2f((ushort)(half ? (wp >> 16) : (wp & 0xffffu)));
            const uint4 u = *(const uint4*)(vb + rix);
            const f32x2 w2 = {wv, wv};
            acc[0] += w2 * __builtin_amdgcn_cvt_pk_f32_fp8((int)u.x, false);
            acc[1] += w2 * __builtin_amdgcn_cvt_pk_f32_fp8((int)u.x, true);
            acc[2] += w2 * __builtin_amdgcn_cvt_pk_f32_fp8((int)u.y, false);
            acc[3] += w2 * __builtin_amdgcn_cvt_pk_f32_fp8((int)u.y, true);
            acc[4] += w2 * __builtin_amdgcn_cvt_pk_f32_fp8((int)u.z, false);
            acc[5] += w2 * __builtin_amdgcn_cvt_pk_f32_fp8((int)u.z, true);
            acc[6] += w2 * __builtin_amdgcn_cvt_pk_f32_fp8((int)u.w, false);
            acc[7] += w2 * __builtin_amdgcn_cvt_pk_f32_fp8((int)u.w, true);
        }
    }

    #pragma unroll
    for (int k = 0; k < 8; k++) {
        acc[k].x += __shfl_xor(acc[k].x, 2);
        acc[k].y += __shfl_xor(acc[k].y, 2);
    }

    f32x2 r0, r1, r2, r3;
    if (half == 0) { r0 = acc[0]; r1 = acc[1]; r2 = acc[2]; r3 = acc[3]; }
    else           { r0 = acc[4]; r1 = acc[5]; r2 = acc[6]; r3 = acc[7]; }

    const int ch_start = (cg & 1) * 16 + half * 8;
    uint4 o;
    o.x = (uint)f2bf(r0.x) | ((uint)f2bf(r0.y) << 16);
    o.y = (uint)f2bf(r1.x) | ((uint)f2bf(r1.y) << 16);
    o.z = (uint)f2bf(r2.x) | ((uint)f2bf(r2.y) << 16);
    o.w = (uint)f2bf(r3.x) | ((uint)f2bf(r3.y) << 16);
    *(uint4*)(samp + (size_t)q * 256 + h * 32 + ch_start) = o;
}

// ---------------------------------------------------------------------------
extern "C" void kernel_launch(void* const* d_in, const int* in_sizes, int n_in,
                              void* d_out, int out_size, void* d_ws, size_t ws_size,
                              hipStream_t stream)
{
    const float* src    = (const float*)d_in[0];
    const float* pos    = (const float*)d_in[1];
    const float* refp   = (const float*)d_in[2];
    const float* W_off  = (const float*)d_in[5];
    const float* b_off  = (const float*)d_in[6];
    const float* W_attn = (const float*)d_in[7];
    const float* b_attn = (const float*)d_in[8];
    const float* W_val  = (const float*)d_in[9];
    const float* b_val  = (const float*)d_in[10];
    const float* W_out  = (const float*)d_in[11];
    const float* b_out  = (const float*)d_in[12];
    const float* g1     = (const float*)d_in[13];
    const float* be1    = (const float*)d_in[14];
    const float* W_ff1  = (const float*)d_in[15];
    const float* b_ff1  = (const float*)d_in[16];
    const float* W_ff2  = (const float*)d_in[17];
    const float* b_ff2  = (const float*)d_in[18];
    const float* g2     = (const float*)d_in[19];
    const float* be2    = (const float*)d_in[20];
    float* out = (float*)d_out;

    const size_t szMDh = (size_t)M_ * 256 * 2;      // 22,282,240 B
    const size_t szOAh = (size_t)M_ * 384 * 2;      // 33,423,360 B

    char* ws = (char*)d_ws;
    ushort* WT      = (ushort*)ws;
    ushort* WT_val  = WT;
    ushort* WT_oa   = WT + 65536;
    ushort* WT_out  = WT + 163840;
    ushort* WT_ff1  = WT + 229376;
    ushort* WT_ff2  = WT + 491520;
    float*  bias_oa = (float*)(ws + 1507328);

    const size_t o_src  = 2097152;
    const size_t o_q    = o_src + szMDh;
    const size_t o_val  = o_q   + szMDh;
    const size_t o_oa   = o_val + szMDh;
    const size_t o_x    = o_oa  + szOAh;
    const size_t o_ffn  = o_x   + szMDh;            // total 146.9 MB (proven fit)

    ushort* src_bf  = (ushort*)(ws + o_src);
    ushort* q_bf    = (ushort*)(ws + o_q);
    ushort* val_f8  = (ushort*)(ws + o_val);
    ushort* offaw   = (ushort*)(ws + o_oa);
    ushort* x_bf    = (ushort*)(ws + o_x);
    ushort* ffn_bf  = (ushort*)(ws + o_ffn);
    ushort* samp_bf = q_bf;      // q_bf dead after offaw GEMM
    ushort* attn_bf = val_f8;    // val dead after sampling
    ushort* hbuf    = src_bf;    // src..oa free after ln1 (100.3 MB >= 89.1)

    // 0) converts (src/q) + all weight transposes, one dispatch
    prep_all<<<CVT_BLOCKS + 2947, 256, 0, stream>>>(
        src, pos, src_bf, q_bf,
        W_val, W_off, W_attn, W_out, W_ff1, W_ff2, b_off, b_attn, WT, bias_oa);
    // 1+2) value GEMM (fp8 head-major) + offaw GEMM, one merged dispatch
    mgemm_vo<<<1700, 256, 0, stream>>>(src_bf, WT_val, b_val, val_f8,
                                       q_bf, WT_oa, bias_oa, offaw);
    // 3) sampling ((b,h)-partitioned, L2-resident)
    sample8<<<16 * 340, 256, 0, stream>>>((const uint8_t*)val_f8, offaw, refp, samp_bf);
    // 4) attn_out = samp @ W_out + b_out
    mgemm<<<2 * (M_ / 128), 256, 0, stream>>>(samp_bf, WT_out, b_out, attn_bf, M_, 256, 256, 0, 0);
    // 5) x = LN(src_bf + attn)
    ln_row<<<M_ / 4, 256, 0, stream>>>(attn_bf, src_bf, g1, be1, nullptr, x_bf);
    // 6) FFN1: h = relu(x @ W_ff1 + b_ff1)
    mgemm<<<8 * (M_ / 128), 256, 0, stream>>>(x_bf, WT_ff1, b_ff1, hbuf, M_, DFF_, 256, 1, 0);
    // 7) FFN2: ffn = h @ W_ff2 + b_ff2
    mgemm<<<2 * (M_ / 128), 256, 0, stream>>>(hbuf, WT_ff2, b_ff2, ffn_bf, M_, 256, DFF_, 0, 0);
    // 8) out = LN(x + ffn)
    ln_row<<<M_ / 4, 256, 0, stream>>>(ffn_bf, x_bf, g2, be2, out, nullptr);
}

// Round 16
// 236.872 us; speedup vs baseline: 1.1319x; 1.0360x over previous
//
#include <hip/hip_runtime.h>
#include <cstdint>
#include <cstddef>

#define B_   2
#define S_   21760
#define M_   (B_ * S_)     // 43520
#define D_   256
#define DFF_ 1024
#define EPS_ 1e-5f

typedef __attribute__((ext_vector_type(8))) short short8;
typedef __attribute__((ext_vector_type(4))) float f32x4;
typedef __attribute__((ext_vector_type(2))) float f32x2;

__device__ __forceinline__ ushort f2bf(float f) {
    uint x = __float_as_uint(f);
    return (ushort)((x + 0x7fffu + ((x >> 16) & 1u)) >> 16);
}
__device__ __forceinline__ float bf2f(ushort u) {
    return __uint_as_float(((uint)u) << 16);
}
__device__ __forceinline__ uint8_t f2f8(float v) {
    return (uint8_t)(__builtin_amdgcn_cvt_pk_fp8_f32(v, v, 0, false) & 0xff);
}
// bijective XCD-chunked swizzle (m204)
__device__ __forceinline__ int xcd_swz(int bid, int nwg) {
    const int q8 = nwg >> 3, r8 = nwg & 7;
    const int xcd = bid & 7, blk = bid >> 3;
    return (xcd < r8 ? xcd * (q8 + 1) : r8 * (q8 + 1) + (xcd - r8) * q8) + blk;
}

// ---------------------------------------------------------------------------
// Merged prep: blocks [0,10880) do src/q bf16 converts; rest do weight
// transpose+convert + bias concat (one dispatch total).
// ---------------------------------------------------------------------------
#define CVT_BLOCKS 10880
__global__ __launch_bounds__(256) void prep_all(
    const float* __restrict__ src, const float* __restrict__ pos,
    ushort* __restrict__ sb, ushort* __restrict__ qb,
    const float* __restrict__ Wval, const float* __restrict__ Woff,
    const float* __restrict__ Wattn, const float* __restrict__ Wout,
    const float* __restrict__ Wff1, const float* __restrict__ Wff2,
    const float* __restrict__ boff, const float* __restrict__ battn,
    ushort* __restrict__ WT, float* __restrict__ bias_oa)
{
    if (blockIdx.x < CVT_BLOCKS) {
        const size_t i = ((size_t)blockIdx.x * 256 + threadIdx.x) * 4;
        const float4 s = *(const float4*)(src + i);
        const float4 p = *(const float4*)(pos + i);
        ushort4 so, qo;
        so.x = f2bf(s.x); so.y = f2bf(s.y); so.z = f2bf(s.z); so.w = f2bf(s.w);
        qo.x = f2bf(s.x + p.x); qo.y = f2bf(s.y + p.y);
        qo.z = f2bf(s.z + p.z); qo.w = f2bf(s.w + p.w);
        *(ushort4*)(sb + i) = so;
        *(ushort4*)(qb + i) = qo;
        return;
    }
    const int i = (blockIdx.x - CVT_BLOCKS) * 256 + threadIdx.x;
    if (i < 65536) {
        const int n = i >> 8, k = i & 255;
        WT[i] = f2bf(Wval[(size_t)k * 256 + n]);
    } else if (i < 163840) {
        const int j = i - 65536;
        const int n = j >> 8, k = j & 255;
        WT[i] = (n < 256) ? f2bf(Woff[(size_t)k * 256 + n])
                          : f2bf(Wattn[(size_t)k * 128 + (n - 256)]);
    } else if (i < 229376) {
        const int j = i - 163840;
        const int n = j >> 8, k = j & 255;
        WT[i] = f2bf(Wout[(size_t)k * 256 + n]);
    } else if (i < 491520) {
        const int j = i - 229376;
        const int n = j >> 8, k = j & 255;
        WT[i] = f2bf(Wff1[(size_t)k * 1024 + n]);
    } else if (i < 753664) {
        const int j = i - 491520;
        const int n = j >> 10, k = j & 1023;
        WT[i] = f2bf(Wff2[(size_t)k * 256 + n]);
    } else if (i < 753664 + 384) {
        const int j = i - 753664;
        bias_oa[j] = (j < 256) ? boff[j] : battn[j - 256];
    }
}

// ---------------------------------------------------------------------------
// Shared bf16 MFMA GEMM body: 128x128 tile, BK=64, XOR-swizzled LDS.
// mode 0: bf16 row-major C. mode 2: fp8 e4m3 head-major value layout.
// ---------------------------------------------------------------------------
__device__ __forceinline__ void gemm_body(
    const ushort* __restrict__ A, const ushort* __restrict__ WT,
    const float* __restrict__ bias, ushort* __restrict__ C,
    int N, int K, int relu, int mode, int wg)
{
    __shared__ __align__(16) ushort Als[128 * 64];
    __shared__ __align__(16) ushort Bls[128 * 64];

    const int gx = N >> 7;
    const int n0 = (wg % gx) << 7;
    const int m0 = (wg / gx) << 7;

    const int tid = threadIdx.x;
    const int wv = tid >> 6, ln = tid & 63;
    const int wm = wv >> 1, wn = wv & 1;

    const int srow = ln >> 3;
    const int scol = ((ln & 7) ^ srow) * 8;

    f32x4 acc[4][4];
    const f32x4 zz = {0.f, 0.f, 0.f, 0.f};
    #pragma unroll
    for (int i = 0; i < 4; i++)
        #pragma unroll
        for (int j = 0; j < 4; j++) acc[i][j] = zz;

    const int fr = ln & 15, qq = ln >> 4;

    for (int k0 = 0; k0 < K; k0 += 64) {
        __syncthreads();
        #pragma unroll
        for (int r = 0; r < 4; ++r) {
            const int c = r * 4 + wv;
            const ushort* ga = A + (size_t)(m0 + c * 8 + srow) * K + k0 + scol;
            __builtin_amdgcn_global_load_lds(
                (const __attribute__((address_space(1))) uint*)ga,
                (__attribute__((address_space(3))) uint*)(Als + c * 512), 16, 0, 0);
            const ushort* gb = WT + (size_t)(n0 + c * 8 + srow) * K + k0 + scol;
            __builtin_amdgcn_global_load_lds(
                (const __attribute__((address_space(1))) uint*)gb,
                (__attribute__((address_space(3))) uint*)(Bls + c * 512), 16, 0, 0);
        }
        __syncthreads();

        #pragma unroll
        for (int kk = 0; kk < 2; kk++) {
            short8 af[4], bfr[4];
            #pragma unroll
            for (int i = 0; i < 4; i++) {
                const int row = wm * 64 + i * 16 + fr;
                af[i] = *(const short8*)&Als[row * 64 + (((kk * 4 + qq) ^ (row & 7)) * 8)];
            }
            #pragma unroll
            for (int j = 0; j < 4; j++) {
                const int row = wn * 64 + j * 16 + fr;
                bfr[j] = *(const short8*)&Bls[row * 64 + (((kk * 4 + qq) ^ (row & 7)) * 8)];
            }
            #pragma unroll
            for (int i = 0; i < 4; i++)
                #pragma unroll
                for (int j = 0; j < 4; j++)
                    acc[i][j] = __builtin_amdgcn_mfma_f32_16x16x32_bf16(
                        af[i], bfr[j], acc[i][j], 0, 0, 0);
        }
    }

    uint8_t* C8 = (uint8_t*)C;
    const int rq = (ln >> 4) * 4;
    #pragma unroll
    for (int j = 0; j < 4; j++) {
        const int col = n0 + wn * 64 + j * 16 + fr;
        const float bv = bias[col];
        #pragma unroll
        for (int i = 0; i < 4; i++) {
            #pragma unroll
            for (int r = 0; r < 4; r++) {
                const int row = m0 + wm * 64 + i * 16 + rq + r;
                float v = acc[i][j][r] + bv;
                if (relu) v = fmaxf(v, 0.f);
                if (mode == 0) {
                    C[(size_t)row * N + col] = f2bf(v);
                } else {
                    const int bb = (row >= S_) ? 1 : 0;
                    const int loc = row - bb * S_;
                    const int hh = col >> 5, ch = col & 31;
                    C8[((size_t)(bb * 8 + hh) * S_ + loc) * 32 + ch] = f2f8(v);
                }
            }
        }
    }
}

// Single-job GEMM kernel
__global__ __launch_bounds__(256) void mgemm(
    const ushort* __restrict__ A, const ushort* __restrict__ WT,
    const float* __restrict__ bias, ushort* __restrict__ C,
    int M, int N, int K, int relu, int mode)
{
    const int wg = xcd_swz(blockIdx.x, gridDim.x);
    gemm_body(A, WT, bias, C, N, K, relu, mode, wg);
}

// Dual-job kernel: blocks [0,680) = value GEMM (mode 2), [680,1700) = offaw.
__global__ __launch_bounds__(256) void mgemm_vo(
    const ushort* __restrict__ src_bf, const ushort* __restrict__ WT_val,
    const float* __restrict__ b_val, ushort* __restrict__ val_f8,
    const ushort* __restrict__ q_bf, const ushort* __restrict__ WT_oa,
    const float* __restrict__ bias_oa, ushort* __restrict__ offaw)
{
    const ushort *A, *WT;
    const float* bias;
    ushort* C;
    int N, mode, wg;
    if (blockIdx.x < 680) {
        A = src_bf; WT = WT_val; bias = b_val; C = val_f8;
        N = 256; mode = 2; wg = xcd_swz(blockIdx.x, 680);
    } else {
        A = q_bf; WT = WT_oa; bias = bias_oa; C = offaw;
        N = 384; mode = 0; wg = xcd_swz(blockIdx.x - 680, 1020);
    }
    gemm_body(A, WT, bias, C, N, 256, 0, mode, wg);
}

// ---------------------------------------------------------------------------
// Residual + LayerNorm, wave-per-row, vectorized, no LDS/barriers.
// ---------------------------------------------------------------------------
__global__ __launch_bounds__(256) void ln_row(
    const ushort* __restrict__ a16, const ushort* __restrict__ r16,
    const float* __restrict__ g, const float* __restrict__ be,
    float* __restrict__ o32, ushort* __restrict__ o16)
{
    const int wv = threadIdx.x >> 6, ln = threadIdx.x & 63;
    const int row = blockIdx.x * 4 + wv;
    const int col = ln * 4;
    const size_t base = (size_t)row * 256 + col;

    const ushort4 av = *(const ushort4*)(a16 + base);
    const ushort4 rv = *(const ushort4*)(r16 + base);
    float v0 = bf2f(av.x) + bf2f(rv.x);
    float v1 = bf2f(av.y) + bf2f(rv.y);
    float v2 = bf2f(av.z) + bf2f(rv.z);
    float v3 = bf2f(av.w) + bf2f(rv.w);

    float s = v0 + v1 + v2 + v3;
    float s2 = v0 * v0 + v1 * v1 + v2 * v2 + v3 * v3;
    #pragma unroll
    for (int o = 32; o > 0; o >>= 1) {
        s  += __shfl_down(s, o);
        s2 += __shfl_down(s2, o);
    }
    s = __shfl(s, 0);
    s2 = __shfl(s2, 0);
    const float mean = s * (1.f / 256.f);
    const float var = s2 * (1.f / 256.f) - mean * mean;
    const float rstd = rsqrtf(var + EPS_);

    const float4 gv = *(const float4*)(g + col);
    const float4 bv = *(const float4*)(be + col);
    const float o0 = (v0 - mean) * rstd * gv.x + bv.x;
    const float o1 = (v1 - mean) * rstd * gv.y + bv.y;
    const float o2 = (v2 - mean) * rstd * gv.z + bv.z;
    const float o3 = (v3 - mean) * rstd * gv.w + bv.w;

    if (o32) {
        float4 o; o.x = o0; o.y = o1; o.z = o2; o.w = o3;
        *(float4*)(o32 + base) = o;
    } else {
        ushort4 o; o.x = f2bf(o0); o.y = f2bf(o1); o.z = f2bf(o2); o.w = f2bf(o3);
        *(ushort4*)(o16 + base) = o;
    }
}

// ---------------------------------------------------------------------------
// Deformable sampling v9: (b,h)-partitioned L2-resident gathers + LDS stash
// of region {index, packed-weight} (replaces 64 ds_bpermute with 32 b64
// broadcast reads) + explicit 8-deep gather batching for MLP.
// Stash stride 33 entries -> conflict-free broadcast reads.
// ---------------------------------------------------------------------------
__global__ __launch_bounds__(256) void sample9(
    const uint8_t* __restrict__ value, const ushort* __restrict__ offaw,
    const float* __restrict__ refp, ushort* __restrict__ samp)
{
    __shared__ uint2 stash[64 * 33];   // 16.9 KB

    const int bid = blockIdx.x;
    const int wg = (bid & 7) * 680 + (bid >> 3);
    const int bh = wg / 340;                      // 0..15
    const int qc = wg - bh * 340;                 // q-chunk
    const int b = bh >> 3, h = bh & 7;

    const int tid = threadIdx.x;
    const int grp = tid >> 2, cg = tid & 3;
    const int q = b * S_ + qc * 64 + grp;         // global row in [0,M)
    const int half = cg >> 1;

    const int Wl = 128 >> cg;
    const float fW = (float)Wl;
    const int st = (cg == 0) ? 0 : (cg == 1) ? 16384 : (cg == 2) ? 20480 : 21504;

    // group softmax: lane cg holds level cg's 4 logits
    const ushort* awq = offaw + (size_t)q * 384 + 256 + h * 16 + cg * 4;
    const uint2 lg = *(const uint2*)awq;
    const float l0 = bf2f((ushort)(lg.x & 0xffff)), l1 = bf2f((ushort)(lg.x >> 16));
    const float l2 = bf2f((ushort)(lg.y & 0xffff)), l3 = bf2f((ushort)(lg.y >> 16));
    float mx = fmaxf(fmaxf(l0, l1), fmaxf(l2, l3));
    mx = fmaxf(mx, __shfl_xor(mx, 1));
    mx = fmaxf(mx, __shfl_xor(mx, 2));
    const float e0 = __expf(l0 - mx), e1 = __expf(l1 - mx);
    const float e2 = __expf(l2 - mx), e3 = __expf(l3 - mx);
    float sm = e0 + e1 + e2 + e3;
    sm += __shfl_xor(sm, 1);
    sm += __shfl_xor(sm, 2);
    const float inv = 1.f / sm;
    const float aj[4] = {e0 * inv, e1 * inv, e2 * inv, e3 * inv};

    // own 4 samples' offsets + reference point
    const ushort* ofq = offaw + (size_t)q * 384 + h * 32 + cg * 8;
    const uint4 of = *(const uint4*)ofq;
    const uint ou[4] = {of.x, of.y, of.z, of.w};
    const float rx = refp[(size_t)q * 8 + cg * 2];
    const float ry = refp[(size_t)q * 8 + cg * 2 + 1];

    // owner math: 8 regions (4 samples x 2 y-rows) -> stash
    #pragma unroll
    for (int j = 0; j < 4; j++) {
        const float ox = bf2f((ushort)(ou[j] & 0xffff));
        const float oy = bf2f((ushort)(ou[j] >> 16));
        const float x = fmaf(rx, fW, ox) - 0.5f;
        const float y = fmaf(ry, fW, oy) - 0.5f;
        const float fx0 = floorf(x), fy0 = floorf(y);
        const float dx = x - fx0, dy = y - fy0;
        const int x0 = (int)fx0, y0 = (int)fy0;

        const int bx = min(max(x0, 0), Wl - 2);
        const float mwx0 = ((x0 >= 0) & (x0 < Wl)) ? (1.f - dx) : 0.f;
        const float mwx1 = ((x0 + 1 >= 0) & (x0 + 1 < Wl)) ? dx : 0.f;
        const int xc0 = min(max(x0, 0), Wl - 1);
        const int xc1 = min(max(x0 + 1, 0), Wl - 1);
        const float wAx = (xc0 == bx ? mwx0 : 0.f) + (xc1 == bx ? mwx1 : 0.f);
        const float wBx = (xc0 == bx + 1 ? mwx0 : 0.f) + (xc1 == bx + 1 ? mwx1 : 0.f);

        const int yc0 = min(max(y0, 0), Wl - 1);
        const int yc1 = min(max(y0 + 1, 0), Wl - 1);
        const float mwy0 = ((y0 >= 0) & (y0 < Wl)) ? (1.f - dy) : 0.f;
        const float mwy1 = ((y0 + 1 >= 0) & (y0 + 1 < Wl)) ? dy : 0.f;

        const float a = aj[j];
        uint2 s0, s1;
        s0.x = (uint)((st + yc0 * Wl + bx) * 32);
        s0.y = (uint)f2bf(a * wAx * mwy0) | ((uint)f2bf(a * wBx * mwy0) << 16);
        s1.x = (uint)((st + yc1 * Wl + bx) * 32);
        s1.y = (uint)f2bf(a * wAx * mwy1) | ((uint)f2bf(a * wBx * mwy1) << 16);
        stash[grp * 33 + cg * 8 + 2 * j]     = s0;
        stash[grp * 33 + cg * 8 + 2 * j + 1] = s1;
    }
    __syncthreads();

    // gather all 32 regions, batched 8-deep for MLP
    const uint8_t* vb = value + (size_t)(b * 8 + h) * S_ * 32 + cg * 16;
    f32x2 acc[8];
    #pragma unroll
    for (int k = 0; k < 8; k++) acc[k] = (f32x2){0.f, 0.f};

    #pragma unroll
    for (int rb = 0; rb < 32; rb += 8) {
        uint2 e[8];
        #pragma unroll
        for (int t2 = 0; t2 < 8; t2++) e[t2] = stash[grp * 33 + rb + t2];
        uint4 u[8];
        #pragma unroll
        for (int t2 = 0; t2 < 8; t2++) u[t2] = *(const uint4*)(vb + e[t2].x);
        #pragma unroll
        for (int t2 = 0; t2 < 8; t2++) {
            const uint wp = e[t2].y;
            const float wv = bf2f((ushort)(half ? (wp >> 16) : (wp & 0xffffu)));
            const f32x2 w2 = {wv, wv};
            acc[0] += w2 * __builtin_amdgcn_cvt_pk_f32_fp8((int)u[t2].x, false);
            acc[1] += w2 * __builtin_amdgcn_cvt_pk_f32_fp8((int)u[t2].x, true);
            acc[2] += w2 * __builtin_amdgcn_cvt_pk_f32_fp8((int)u[t2].y, false);
            acc[3] += w2 * __builtin_amdgcn_cvt_pk_f32_fp8((int)u[t2].y, true);
            acc[4] += w2 * __builtin_amdgcn_cvt_pk_f32_fp8((int)u[t2].z, false);
            acc[5] += w2 * __builtin_amdgcn_cvt_pk_f32_fp8((int)u[t2].z, true);
            acc[6] += w2 * __builtin_amdgcn_cvt_pk_f32_fp8((int)u[t2].w, false);
            acc[7] += w2 * __builtin_amdgcn_cvt_pk_f32_fp8((int)u[t2].w, true);
        }
    }

    // combine the two x-halves (lanes cg and cg^2 hold same 16 channels)
    #pragma unroll
    for (int k = 0; k < 8; k++) {
        acc[k].x += __shfl_xor(acc[k].x, 2);
        acc[k].y += __shfl_xor(acc[k].y, 2);
    }

    f32x2 r0, r1, r2, r3;
    if (half == 0) { r0 = acc[0]; r1 = acc[1]; r2 = acc[2]; r3 = acc[3]; }
    else           { r0 = acc[4]; r1 = acc[5]; r2 = acc[6]; r3 = acc[7]; }

    const int ch_start = (cg & 1) * 16 + half * 8;
    uint4 o;
    o.x = (uint)f2bf(r0.x) | ((uint)f2bf(r0.y) << 16);
    o.y = (uint)f2bf(r1.x) | ((uint)f2bf(r1.y) << 16);
    o.z = (uint)f2bf(r2.x) | ((uint)f2bf(r2.y) << 16);
    o.w = (uint)f2bf(r3.x) | ((uint)f2bf(r3.y) << 16);
    *(uint4*)(samp + (size_t)q * 256 + h * 32 + ch_start) = o;
}

// ---------------------------------------------------------------------------
extern "C" void kernel_launch(void* const* d_in, const int* in_sizes, int n_in,
                              void* d_out, int out_size, void* d_ws, size_t ws_size,
                              hipStream_t stream)
{
    const float* src    = (const float*)d_in[0];
    const float* pos    = (const float*)d_in[1];
    const float* refp   = (const float*)d_in[2];
    const float* W_off  = (const float*)d_in[5];
    const float* b_off  = (const float*)d_in[6];
    const float* W_attn = (const float*)d_in[7];
    const float* b_attn = (const float*)d_in[8];
    const float* W_val  = (const float*)d_in[9];
    const float* b_val  = (const float*)d_in[10];
    const float* W_out  = (const float*)d_in[11];
    const float* b_out  = (const float*)d_in[12];
    const float* g1     = (const float*)d_in[13];
    const float* be1    = (const float*)d_in[14];
    const float* W_ff1  = (const float*)d_in[15];
    const float* b_ff1  = (const float*)d_in[16];
    const float* W_ff2  = (const float*)d_in[17];
    const float* b_ff2  = (const float*)d_in[18];
    const float* g2     = (const float*)d_in[19];
    const float* be2    = (const float*)d_in[20];
    float* out = (float*)d_out;

    const size_t szMDh = (size_t)M_ * 256 * 2;      // 22,282,240 B
    const size_t szOAh = (size_t)M_ * 384 * 2;      // 33,423,360 B

    char* ws = (char*)d_ws;
    ushort* WT      = (ushort*)ws;
    ushort* WT_val  = WT;
    ushort* WT_oa   = WT + 65536;
    ushort* WT_out  = WT + 163840;
    ushort* WT_ff1  = WT + 229376;
    ushort* WT_ff2  = WT + 491520;
    float*  bias_oa = (float*)(ws + 1507328);

    const size_t o_src  = 2097152;
    const size_t o_q    = o_src + szMDh;
    const size_t o_val  = o_q   + szMDh;
    const size_t o_oa   = o_val + szMDh;
    const size_t o_x    = o_oa  + szOAh;
    const size_t o_ffn  = o_x   + szMDh;            // total 146.9 MB (proven fit)

    ushort* src_bf  = (ushort*)(ws + o_src);
    ushort* q_bf    = (ushort*)(ws + o_q);
    ushort* val_f8  = (ushort*)(ws + o_val);
    ushort* offaw   = (ushort*)(ws + o_oa);
    ushort* x_bf    = (ushort*)(ws + o_x);
    ushort* ffn_bf  = (ushort*)(ws + o_ffn);
    ushort* samp_bf = q_bf;      // q_bf dead after offaw GEMM
    ushort* attn_bf = val_f8;    // val dead after sampling
    ushort* hbuf    = src_bf;    // src..oa free after ln1 (100.3 MB >= 89.1)

    // 0) converts (src/q) + all weight transposes, one dispatch
    prep_all<<<CVT_BLOCKS + 2947, 256, 0, stream>>>(
        src, pos, src_bf, q_bf,
        W_val, W_off, W_attn, W_out, W_ff1, W_ff2, b_off, b_attn, WT, bias_oa);
    // 1+2) value GEMM (fp8 head-major) + offaw GEMM, one merged dispatch
    mgemm_vo<<<1700, 256, 0, stream>>>(src_bf, WT_val, b_val, val_f8,
                                       q_bf, WT_oa, bias_oa, offaw);
    // 3) sampling ((b,h)-partitioned, LDS-stash + batched gathers)
    sample9<<<16 * 340, 256, 0, stream>>>((const uint8_t*)val_f8, offaw, refp, samp_bf);
    // 4) attn_out = samp @ W_out + b_out
    mgemm<<<2 * (M_ / 128), 256, 0, stream>>>(samp_bf, WT_out, b_out, attn_bf, M_, 256, 256, 0, 0);
    // 5) x = LN(src_bf + attn)
    ln_row<<<M_ / 4, 256, 0, stream>>>(attn_bf, src_bf, g1, be1, nullptr, x_bf);
    // 6) FFN1: h = relu(x @ W_ff1 + b_ff1)
    mgemm<<<8 * (M_ / 128), 256, 0, stream>>>(x_bf, WT_ff1, b_ff1, hbuf, M_, DFF_, 256, 1, 0);
    // 7) FFN2: ffn = h @ W_ff2 + b_ff2
    mgemm<<<2 * (M_ / 128), 256, 0, stream>>>(hbuf, WT_ff2, b_ff2, ffn_bf, M_, 256, DFF_, 0, 0);
    // 8) out = LN(x + ffn)
    ln_row<<<M_ / 4, 256, 0, stream>>>(ffn_bf, x_bf, g2, be2, out, nullptr);
}